// Round 1
// baseline (380.315 us; speedup 1.0000x reference)
//
#include <hip/hip_runtime.h>

// TensorProduct: 128x0e+128x1o (x1) ⊗ 1x0e+1x1o (x2) -> 128x0e+128x1o, 'uvw' weights.
//
// Folded formulation (scalars b into A-rows, norms into weights):
//   out0[z,w]      = [b0*a0 ; a1·b1]   @ V0,  V0 = [W0/16 ; W3/(16*sqrt3)]  (256x128)
//   out1[z,w,k]    = [b1k*a0 ; b0*a1k] @ V1,  V1 = [W1/16 ; W2/16]          (256x128)
// One bf16 GEMM, K=256, N=128, M=4Z. Memory floor ~65us (411MB @ 6.3TB/s);
// MFMA compute ~13us -> memory-bound by design.
//
// Structure: 512 thr/block (8 waves). Wave w owns N-tile w (16 cols) and keeps
// its B-frags (2 mats x 8 k-steps x 16B) resident in 64 VGPRs, loaded once from
// L2. Per 32-z tile: stage folded bf16 A-rows (128 rows x 256 k) into 64KB LDS
// in MFMA A-frag order (16B/lane contiguous, XOR-swizzled by row&7 to keep
// reads/writes at the 8-cyc LDS floor), then 64 mfma_f32_16x16x32_bf16 per
// wave. Scales folded into weights -> epilogue is a plain store.
// C/D layout (m89-verified): col = lane&15 (=n), row = (lane>>4)*4 + reg (=m).

#define Z_TOTAL   100000
#define BM        32
#define NTILES_Z  (Z_TOTAL / BM)   // 3125, exact
#define GRID      512
#define THREADS   512

using bf16x8 = __attribute__((ext_vector_type(8))) __bf16;
using f32x4  = __attribute__((ext_vector_type(4))) float;
using u16x8  = __attribute__((ext_vector_type(8))) unsigned short;

__device__ __forceinline__ unsigned short f2bf(float f) {
    // RNE truncation to bf16 (inputs are finite gaussians; no NaN handling needed)
    unsigned int u = __builtin_bit_cast(unsigned int, f);
    u += 0x7fffu + ((u >> 16) & 1u);
    return (unsigned short)(u >> 16);
}

// LDS: 128 rows x 256 bf16 (512B rows). chunk = 16B unit index (0..31).
// XOR-swizzle low 3 bits of chunk by (row&7): keeps k<128 vs k>=128 halves
// intact and gives conflict-floor access for both staging writes and A-reads.
__device__ __forceinline__ int lds_idx(int row, int chunk) {
    return row * 256 + ((chunk ^ (row & 7)) << 3);
}

__global__ __launch_bounds__(THREADS, 4)
void tp_kernel(const float* __restrict__ x1, const float* __restrict__ x2,
               const float* __restrict__ wts, float* __restrict__ out)
{
    __shared__ __align__(16) unsigned short lds[128 * 256];   // 64 KB

    const int t    = threadIdx.x;
    const int lane = t & 63;
    const int wv   = t >> 6;        // wave id 0..7 == n-tile
    const int m16  = lane & 15;
    const int q    = lane >> 4;

    // ---- persistent B fragments (weights), 64 VGPRs/lane ----
    const float S16 = 0.0625f;                                // 1/16
    const float S48 = 0.0625f * 0.57735026918962576f;         // 1/(16*sqrt(3))
    bf16x8 Bf[2][8];
    {
        const int n = wv * 16 + m16;
        #pragma unroll
        for (int mat = 0; mat < 2; ++mat) {
            #pragma unroll
            for (int kt = 0; kt < 8; ++kt) {
                u16x8 bb;
                #pragma unroll
                for (int j = 0; j < 8; ++j) {
                    const int k = kt * 32 + q * 8 + j;
                    float v;
                    if (mat == 0) {  // V0 = [W0/16 ; W3/(16*sqrt3)]
                        v = (k < 128) ? wts[k * 128 + n] * S16
                                      : wts[49152 + (k - 128) * 128 + n] * S48;
                    } else {         // V1 = [W1/16 ; W2/16]
                        v = (k < 128) ? wts[16384 + k * 128 + n] * S16
                                      : wts[32768 + (k - 128) * 128 + n] * S16;
                    }
                    bb[j] = f2bf(v);
                }
                Bf[mat][kt] = __builtin_bit_cast(bf16x8, bb);
            }
        }
    }

    const int zl = t >> 4;          // local z row 0..31
    const int ug = t & 15;          // u-group (8 u's per thread)
    const int u0 = ug * 8;

    for (int tile = blockIdx.x; tile < NTILES_Z; tile += gridDim.x) {
        const int z0 = tile * BM;
        const float* xr = x1 + (size_t)(z0 + zl) * 512;

        __syncthreads();            // guard LDS vs previous iteration's reads
        {
            const float4 b4 = *(const float4*)(x2 + (size_t)(z0 + zl) * 4);
            const float b0 = b4.x, b1x = b4.y, b1y = b4.z, b1z = b4.w;

            // a0 chunk: 8 floats (coalesced: 16 lanes cover a 512B row segment)
            const float4 a0a = *(const float4*)(xr + u0);
            const float4 a0b = *(const float4*)(xr + u0 + 4);
            const float a0[8] = {a0a.x, a0a.y, a0a.z, a0a.w,
                                 a0b.x, a0b.y, a0b.z, a0b.w};
            u16x8 pk;
            #pragma unroll
            for (int i = 0; i < 8; ++i) pk[i] = f2bf(b0 * a0[i]);
            *(u16x8*)&lds[lds_idx(zl, ug)] = pk;              // R0 lo: b0*a0
            #pragma unroll
            for (int i = 0; i < 8; ++i) pk[i] = f2bf(b1x * a0[i]);
            *(u16x8*)&lds[lds_idx(32 + zl, ug)] = pk;         // R1x lo
            #pragma unroll
            for (int i = 0; i < 8; ++i) pk[i] = f2bf(b1y * a0[i]);
            *(u16x8*)&lds[lds_idx(64 + zl, ug)] = pk;         // R1y lo
            #pragma unroll
            for (int i = 0; i < 8; ++i) pk[i] = f2bf(b1z * a0[i]);
            *(u16x8*)&lds[lds_idx(96 + zl, ug)] = pk;         // R1z lo

            // a1 chunk: 24 floats, interleaved (u,3)
            float a1[24];
            #pragma unroll
            for (int i = 0; i < 6; ++i) {
                const float4 v = *(const float4*)(xr + 128 + u0 * 3 + i * 4);
                a1[i*4+0] = v.x; a1[i*4+1] = v.y; a1[i*4+2] = v.z; a1[i*4+3] = v.w;
            }
            #pragma unroll
            for (int i = 0; i < 8; ++i)                       // R0 hi: a1·b1 (1/sqrt3 in V0)
                pk[i] = f2bf(a1[3*i]*b1x + a1[3*i+1]*b1y + a1[3*i+2]*b1z);
            *(u16x8*)&lds[lds_idx(zl, 16 + ug)] = pk;
            #pragma unroll
            for (int i = 0; i < 8; ++i) pk[i] = f2bf(b0 * a1[3*i + 0]);
            *(u16x8*)&lds[lds_idx(32 + zl, 16 + ug)] = pk;    // R1x hi: b0*a1x
            #pragma unroll
            for (int i = 0; i < 8; ++i) pk[i] = f2bf(b0 * a1[3*i + 1]);
            *(u16x8*)&lds[lds_idx(64 + zl, 16 + ug)] = pk;    // R1y hi
            #pragma unroll
            for (int i = 0; i < 8; ++i) pk[i] = f2bf(b0 * a1[3*i + 2]);
            *(u16x8*)&lds[lds_idx(96 + zl, 16 + ug)] = pk;    // R1z hi
        }
        __syncthreads();

        // ---- MFMA: 8 M-tiles (out0 z0/z1, then (k,zt) for out1) ----
        const int n = wv * 16 + m16;
        #pragma unroll
        for (int mt = 0; mt < 8; ++mt) {
            const int isV1 = (mt >= 2) ? 1 : 0;
            const int k3 = isV1 ? ((mt - 2) >> 1) : 0;
            const int zt = isV1 ? ((mt - 2) & 1) : 0;
            const int rbase = isV1 ? (32 + k3 * 32 + zt * 16) : (mt * 16);
            const int r = rbase + m16;     // A-row for this lane
            f32x4 acc = {0.f, 0.f, 0.f, 0.f};
            #pragma unroll
            for (int kt = 0; kt < 8; ++kt) {
                const bf16x8 a = __builtin_bit_cast(bf16x8,
                    *(const u16x8*)&lds[lds_idx(r, kt * 4 + q)]);
                acc = __builtin_amdgcn_mfma_f32_16x16x32_bf16(a, Bf[isV1][kt], acc, 0, 0, 0);
            }
            if (!isV1) {                   // out0: out[z, n]
                #pragma unroll
                for (int reg = 0; reg < 4; ++reg) {
                    const int z = z0 + mt * 16 + q * 4 + reg;
                    out[(size_t)z * 512 + n] = acc[reg];
                }
            } else {                       // out1: out[z, 128 + 3n + k]
                #pragma unroll
                for (int reg = 0; reg < 4; ++reg) {
                    const int z = z0 + zt * 16 + q * 4 + reg;
                    out[(size_t)z * 512 + 128 + n * 3 + k3] = acc[reg];
                }
            }
        }
    }
}

extern "C" void kernel_launch(void* const* d_in, const int* in_sizes, int n_in,
                              void* d_out, int out_size, void* d_ws, size_t ws_size,
                              hipStream_t stream) {
    (void)in_sizes; (void)n_in; (void)d_ws; (void)ws_size; (void)out_size;
    const float* x1  = (const float*)d_in[0];
    const float* x2  = (const float*)d_in[1];
    const float* wts = (const float*)d_in[2];
    float* out = (float*)d_out;
    tp_kernel<<<dim3(GRID), dim3(THREADS), 0, stream>>>(x1, x2, wts, out);
}